// Round 1
// 492.676 us; speedup vs baseline: 1.0390x; 1.0390x over previous
//
#include <hip/hip_runtime.h>
#include <hip/hip_bf16.h>

typedef __attribute__((ext_vector_type(8))) short short8;
typedef __attribute__((ext_vector_type(4))) short short4v;
typedef __attribute__((ext_vector_type(4))) float floatx4;

#define N_CELLS  500000
#define B_SAMP   512
#define D_X      128
#define D_Z      32
#define D_IN     160
#define H_DIM    256
#define D_OUT    16

#define M_TILE   64
#define NBLK     7813          // ceil(500000/64); last block has 32 valid cells
#define LDH      264           // padded LDS row stride (bf16): 528B rows, 16B-aligned

#define NREP     64            // accumulator replicas to spread atomic contention

// workspace layout (bytes); all 16B aligned
#define OFF_W1P   0            // 16*5*512 bf16 = 81920 B
#define OFF_W2P   81920        // 16*8*512 bf16 = 131072 B
#define OFF_W3P   212992       // 1*8*512 bf16 = 8192 B
#define OFF_ACC   221184       // NREP*8192*4 = 2097152 B
#define OFF_CNT   2318336      // NREP*512*4  = 131072 B

#define ZERO_BLKS 2176         // 2176*256 = 557056 = NREP*(8192+512) floats
#define W1_BLKS   160          // 40960 elems
#define W2_BLKS   256          // 65536 elems
#define W3_BLKS   16           // 4096 elems

__device__ __forceinline__ short bfb(float x) {
    union { __hip_bfloat16 h; short s; } u;
    u.h = __float2bfloat16(x);
    return u.s;
}

// merged prep: zero accumulators + pack all three weights into MFMA fragment order
// packed[((t*kS+s)*64+L)*8+j] = W[(s*32+(L>>4)*8+j)*N + t*16+(L&15)]
// W1 rows k<128 are pre-scaled by ln2 so staging can use raw v_log_f32 (log2).
__global__ __launch_bounds__(256)
void prep(const float* __restrict__ W1, const float* __restrict__ W2,
          const float* __restrict__ W3,
          __hip_bfloat16* __restrict__ w1p, __hip_bfloat16* __restrict__ w2p,
          __hip_bfloat16* __restrict__ w3p, float* __restrict__ accs) {
    int bid = blockIdx.x;
    if (bid < ZERO_BLKS) {
        accs[bid * 256 + threadIdx.x] = 0.0f;   // covers accs + cnts (contiguous)
        return;
    }
    const float* W; __hip_bfloat16* dst; int N, kS, idx, scaleK;
    if (bid < ZERO_BLKS + W1_BLKS) {
        idx = (bid - ZERO_BLKS) * 256 + threadIdx.x;
        W = W1; dst = w1p; N = H_DIM; kS = 5; scaleK = 128;
    } else if (bid < ZERO_BLKS + W1_BLKS + W2_BLKS) {
        idx = (bid - ZERO_BLKS - W1_BLKS) * 256 + threadIdx.x;
        W = W2; dst = w2p; N = H_DIM; kS = 8; scaleK = 0;
    } else {
        idx = (bid - ZERO_BLKS - W1_BLKS - W2_BLKS) * 256 + threadIdx.x;
        W = W3; dst = w3p; N = D_OUT; kS = 8; scaleK = 0;
    }
    int j = idx & 7;
    int L = (idx >> 3) & 63;
    int s = (idx >> 9) % kS;
    int t = idx / (kS << 9);
    int k = s * 32 + ((L >> 4) << 3) + j;
    int n = t * 16 + (L & 15);
    float v = W[(size_t)k * N + n];
    if (k < scaleK) v *= 0.6931471805599453f;
    dst[idx] = __float2bfloat16(v);
}

// 64 cells/block, 512 threads (8 waves: 2 cell-halves x 4 N-quarters).
// Operand-swapped MFMA: D = mfma(Wfrag_as_A, cells_as_B) puts 4 consecutive
// output features in each thread's regs -> packed b64 epilogue stores, bias
// folded into accumulator init. LDS: sA = Xp then H1 (aliased), sB = H0.
__global__ __launch_bounds__(512, 4)
void fused_mlp(const float* __restrict__ X, const float* __restrict__ Z,
               const int* __restrict__ c2b, const int* __restrict__ sidx,
               const float* __restrict__ b1, const float* __restrict__ b2,
               const float* __restrict__ b3,
               const __hip_bfloat16* __restrict__ w1p,
               const __hip_bfloat16* __restrict__ w2p,
               const __hip_bfloat16* __restrict__ w3p,
               float* __restrict__ accs, float* __restrict__ cnts) {
    __shared__ __hip_bfloat16 sA[M_TILE][LDH];   // Xp (cols 0..159), later H1
    __shared__ __hip_bfloat16 sB[M_TILE][LDH];   // H0

    const int tid = threadIdx.x;
    const int w   = tid >> 6;     // wave 0..7
    const int L   = tid & 63;
    const int q   = L >> 4;       // quad 0..3
    const int ln  = L & 15;
    const int wm  = w >> 2;       // cell-half 0..1
    const int wn  = w & 3;        // N-quarter 0..3
    const int base = blockIdx.x * M_TILE;

    // ---- stage Xp = [log2(1+X) | Z[c2b]] as bf16 (packed b64 writes) ----
#pragma unroll
    for (int i = 0; i < 4; ++i) {
        int idx = tid + i * 512;          // 64 rows * 32 float4
        int row = idx >> 5;
        int c4  = idx & 31;
        int gr = base + row; if (gr >= N_CELLS) gr = N_CELLS - 1;   // tail clamp
        float4 v = *(const float4*)(X + (size_t)gr * D_X + c4 * 4);
        short4v pk;
        pk.x = bfb(__log2f(1.0f + v.x));
        pk.y = bfb(__log2f(1.0f + v.y));
        pk.z = bfb(__log2f(1.0f + v.z));
        pk.w = bfb(__log2f(1.0f + v.w));
        *(short4v*)&sA[row][c4 * 4] = pk;
    }
    {
        int row = tid >> 3;               // 64 rows
        int c0  = (tid & 7) * 4;          // D_Z = 32 -> 8 groups
        int gr = base + row; if (gr >= N_CELLS) gr = N_CELLS - 1;
        int b  = c2b[gr];
        float4 v = *(const float4*)(Z + (size_t)b * D_Z + c0);
        short4v pk;
        pk.x = bfb(v.x); pk.y = bfb(v.y); pk.z = bfb(v.z); pk.w = bfb(v.w);
        *(short4v*)&sA[row][D_X + c0] = pk;
    }
    __syncthreads();

    floatx4 acc[2][4];

    // ---- GEMM1: h0 = relu(Xp @ W1 + b1), swapped operands, bias in C-init ----
#pragma unroll
    for (int nt = 0; nt < 4; ++nt) {
        float4 bv = *(const float4*)(b1 + wn * 64 + nt * 16 + q * 4);
        acc[0][nt] = (floatx4){bv.x, bv.y, bv.z, bv.w};
        acc[1][nt] = acc[0][nt];
    }
#pragma unroll
    for (int s = 0; s < 5; ++s) {
        short8 x0 = *(const short8*)&sA[wm * 32 + ln][s * 32 + q * 8];
        short8 x1 = *(const short8*)&sA[wm * 32 + 16 + ln][s * 32 + q * 8];
#pragma unroll
        for (int nt = 0; nt < 4; ++nt) {
            int t = wn * 4 + nt;
            short8 wf = *(const short8*)(w1p + (size_t)(((t * 5 + s) << 6) + L) * 8);
            acc[0][nt] = __builtin_amdgcn_mfma_f32_16x16x32_bf16(wf, x0, acc[0][nt], 0, 0, 0);
            acc[1][nt] = __builtin_amdgcn_mfma_f32_16x16x32_bf16(wf, x1, acc[1][nt], 0, 0, 0);
        }
    }
    // epilogue: 4 consecutive n per thread -> one b64 store each
#pragma unroll
    for (int mt = 0; mt < 2; ++mt)
#pragma unroll
        for (int nt = 0; nt < 4; ++nt) {
            short4v pk;
            pk.x = bfb(fmaxf(acc[mt][nt][0], 0.0f));
            pk.y = bfb(fmaxf(acc[mt][nt][1], 0.0f));
            pk.z = bfb(fmaxf(acc[mt][nt][2], 0.0f));
            pk.w = bfb(fmaxf(acc[mt][nt][3], 0.0f));
            *(short4v*)&sB[wm * 32 + mt * 16 + ln][wn * 64 + nt * 16 + q * 4] = pk;
        }
    __syncthreads();

    // ---- GEMM2: h1 = relu(h0 @ W2 + b2) -> sA (Xp region dead) ----
#pragma unroll
    for (int nt = 0; nt < 4; ++nt) {
        float4 bv = *(const float4*)(b2 + wn * 64 + nt * 16 + q * 4);
        acc[0][nt] = (floatx4){bv.x, bv.y, bv.z, bv.w};
        acc[1][nt] = acc[0][nt];
    }
#pragma unroll
    for (int s = 0; s < 8; ++s) {
        short8 x0 = *(const short8*)&sB[wm * 32 + ln][s * 32 + q * 8];
        short8 x1 = *(const short8*)&sB[wm * 32 + 16 + ln][s * 32 + q * 8];
#pragma unroll
        for (int nt = 0; nt < 4; ++nt) {
            int t = wn * 4 + nt;
            short8 wf = *(const short8*)(w2p + (size_t)(((t * 8 + s) << 6) + L) * 8);
            acc[0][nt] = __builtin_amdgcn_mfma_f32_16x16x32_bf16(wf, x0, acc[0][nt], 0, 0, 0);
            acc[1][nt] = __builtin_amdgcn_mfma_f32_16x16x32_bf16(wf, x1, acc[1][nt], 0, 0, 0);
        }
    }
#pragma unroll
    for (int mt = 0; mt < 2; ++mt)
#pragma unroll
        for (int nt = 0; nt < 4; ++nt) {
            short4v pk;
            pk.x = bfb(fmaxf(acc[mt][nt][0], 0.0f));
            pk.y = bfb(fmaxf(acc[mt][nt][1], 0.0f));
            pk.z = bfb(fmaxf(acc[mt][nt][2], 0.0f));
            pk.w = bfb(fmaxf(acc[mt][nt][3], 0.0f));
            *(short4v*)&sA[wm * 32 + mt * 16 + ln][wn * 64 + nt * 16 + q * 4] = pk;
        }
    __syncthreads();

    // ---- GEMM3: waves 0..3, 16 cells each, full K=256; atomics from regs ----
    if (w < 4) {
        float4 bv = *(const float4*)(b3 + q * 4);
        floatx4 a3 = (floatx4){bv.x, bv.y, bv.z, bv.w};
#pragma unroll
        for (int s = 0; s < 8; ++s) {
            short8 h  = *(const short8*)&sA[w * 16 + ln][s * 32 + q * 8];
            short8 wf = *(const short8*)(w3p + (size_t)((s << 6) + L) * 8);
            a3 = __builtin_amdgcn_mfma_f32_16x16x32_bf16(wf, h, a3, 0, 0, 0);
        }
        int cell = base + w * 16 + ln;
        if (cell < N_CELLS) {
            int b = c2b[cell];
            int so = sidx[b];
            int rep = blockIdx.x & (NREP - 1);
            float* dst = accs + (size_t)rep * (B_SAMP * D_OUT) + (size_t)so * D_OUT + q * 4;
            atomicAdd(dst + 0, a3[0]);
            atomicAdd(dst + 1, a3[1]);
            atomicAdd(dst + 2, a3[2]);
            atomicAdd(dst + 3, a3[3]);
            if (q == 0) atomicAdd(cnts + (size_t)rep * B_SAMP + so, 1.0f);
        }
    }
}

__global__ __launch_bounds__(256)
void finalize(const float* __restrict__ accs, const float* __restrict__ cnts,
              float* __restrict__ out) {
    int o = blockIdx.x * blockDim.x + threadIdx.x;   // 0..8191
    int s = o >> 4;
    float sum = 0.f, cnt = 0.f;
#pragma unroll 8
    for (int r = 0; r < NREP; ++r) {
        sum += accs[(size_t)r * (B_SAMP * D_OUT) + o];
        cnt += cnts[(size_t)r * B_SAMP + s];
    }
    out[o] = sum / fmaxf(cnt, 1.0f);
}

extern "C" void kernel_launch(void* const* d_in, const int* in_sizes, int n_in,
                              void* d_out, int out_size, void* d_ws, size_t ws_size,
                              hipStream_t stream) {
    const float* X   = (const float*)d_in[0];
    const float* Z   = (const float*)d_in[1];
    const float* W1  = (const float*)d_in[2];
    const float* b1  = (const float*)d_in[3];
    const float* W2  = (const float*)d_in[4];
    const float* b2  = (const float*)d_in[5];
    const float* W3  = (const float*)d_in[6];
    const float* b3  = (const float*)d_in[7];
    const int*   c2b = (const int*)d_in[8];
    const int*   sidx= (const int*)d_in[9];

    char* ws = (char*)d_ws;
    __hip_bfloat16* w1p = (__hip_bfloat16*)(ws + OFF_W1P);
    __hip_bfloat16* w2p = (__hip_bfloat16*)(ws + OFF_W2P);
    __hip_bfloat16* w3p = (__hip_bfloat16*)(ws + OFF_W3P);
    float* accs = (float*)(ws + OFF_ACC);
    float* cnts = (float*)(ws + OFF_CNT);
    float* out  = (float*)d_out;

    // one merged prep launch: zero replicated accumulators + pack weights
    prep<<<ZERO_BLKS + W1_BLKS + W2_BLKS + W3_BLKS, 256, 0, stream>>>(
        W1, W2, W3, w1p, w2p, w3p, accs);

    fused_mlp<<<NBLK, 512, 0, stream>>>(X, Z, c2b, sidx, b1, b2, b3,
                                        w1p, w2p, w3p, accs, cnts);
    finalize<<<32, 256, 0, stream>>>(accs, cnts, out);
}